// Round 1
// baseline (8422.730 us; speedup 1.0000x reference)
//
#include <hip/hip_runtime.h>
#include <hip/hip_bf16.h>
#include <math.h>

#define T_TOK 2048
#define H_DIM 4096
#define N_HEADS 32
#define QK_HEAD 192
#define SCALE_F 0.07216878364870323f  // 192^-0.5
#define NEG_BIG -1e30f

// ---------------- 128x128 fp32 GEMM (row-major, C = A@B) ----------------
__global__ __launch_bounds__(256) void gemm_f32_128(
    const float* __restrict__ A, const float* __restrict__ B, float* __restrict__ C,
    int K, int lda, int ldb, int ldc)
{
    __shared__ float As[16][132];
    __shared__ float Bs[16][132];
    const int tid = threadIdx.x;
    const int row0 = blockIdx.y * 128, col0 = blockIdx.x * 128;
    const int tx = tid & 15, ty = tid >> 4;
    const int am = tid >> 2, akq = (tid & 3) * 4;
    const int bk = tid >> 5, bn = (tid & 31) * 4;

    float acc[8][8];
    #pragma unroll
    for (int i = 0; i < 8; i++)
        #pragma unroll
        for (int j = 0; j < 8; j++) acc[i][j] = 0.f;

    for (int k0 = 0; k0 < K; k0 += 16) {
        float4 a0 = *(const float4*)&A[(size_t)(row0 + am) * lda + k0 + akq];
        float4 a1 = *(const float4*)&A[(size_t)(row0 + am + 64) * lda + k0 + akq];
        float4 b0 = *(const float4*)&B[(size_t)(k0 + bk) * ldb + col0 + bn];
        float4 b1 = *(const float4*)&B[(size_t)(k0 + bk + 8) * ldb + col0 + bn];
        __syncthreads();
        As[akq + 0][am] = a0.x; As[akq + 1][am] = a0.y;
        As[akq + 2][am] = a0.z; As[akq + 3][am] = a0.w;
        As[akq + 0][am + 64] = a1.x; As[akq + 1][am + 64] = a1.y;
        As[akq + 2][am + 64] = a1.z; As[akq + 3][am + 64] = a1.w;
        *(float4*)&Bs[bk][bn] = b0;
        *(float4*)&Bs[bk + 8][bn] = b1;
        __syncthreads();
        #pragma unroll
        for (int kk = 0; kk < 16; kk++) {
            float4 av0 = *(float4*)&As[kk][ty * 8];
            float4 av1 = *(float4*)&As[kk][ty * 8 + 4];
            float4 bv0 = *(float4*)&Bs[kk][tx * 8];
            float4 bv1 = *(float4*)&Bs[kk][tx * 8 + 4];
            float a[8] = {av0.x, av0.y, av0.z, av0.w, av1.x, av1.y, av1.z, av1.w};
            float b[8] = {bv0.x, bv0.y, bv0.z, bv0.w, bv1.x, bv1.y, bv1.z, bv1.w};
            #pragma unroll
            for (int i = 0; i < 8; i++)
                #pragma unroll
                for (int j = 0; j < 8; j++) acc[i][j] += a[i] * b[j];
        }
    }
    #pragma unroll
    for (int i = 0; i < 8; i++) {
        float* cp = &C[(size_t)(row0 + ty * 8 + i) * ldc + col0 + tx * 8];
        *(float4*)cp = make_float4(acc[i][0], acc[i][1], acc[i][2], acc[i][3]);
        *(float4*)(cp + 4) = make_float4(acc[i][4], acc[i][5], acc[i][6], acc[i][7]);
    }
}

// ------------- 64x64 fp32 GEMM, batched; BT=1 => C = A@B^T --------------
template<int BT>
__global__ __launch_bounds__(256) void gemm_f32_64(
    const float* __restrict__ A, const float* __restrict__ B, float* __restrict__ C,
    int K, int lda, int ldb, int ldc, long sA, long sB, long sC)
{
    const int bz = blockIdx.z;
    A += (size_t)bz * sA; B += (size_t)bz * sB; C += (size_t)bz * sC;
    __shared__ float As[16][68];
    __shared__ float Bs[16][68];
    const int tid = threadIdx.x;
    const int row0 = blockIdx.y * 64, col0 = blockIdx.x * 64;
    const int tx = tid & 15, ty = tid >> 4;
    const int lm = tid >> 2, lkq = (tid & 3) * 4;

    float acc[4][4];
    #pragma unroll
    for (int i = 0; i < 4; i++)
        #pragma unroll
        for (int j = 0; j < 4; j++) acc[i][j] = 0.f;

    for (int k0 = 0; k0 < K; k0 += 16) {
        float4 a0 = *(const float4*)&A[(size_t)(row0 + lm) * lda + k0 + lkq];
        float4 b0;
        if (BT) b0 = *(const float4*)&B[(size_t)(col0 + lm) * ldb + k0 + lkq];
        else    b0 = *(const float4*)&B[(size_t)(k0 + (tid >> 4)) * ldb + col0 + (tid & 15) * 4];
        __syncthreads();
        As[lkq + 0][lm] = a0.x; As[lkq + 1][lm] = a0.y;
        As[lkq + 2][lm] = a0.z; As[lkq + 3][lm] = a0.w;
        if (BT) {
            Bs[lkq + 0][lm] = b0.x; Bs[lkq + 1][lm] = b0.y;
            Bs[lkq + 2][lm] = b0.z; Bs[lkq + 3][lm] = b0.w;
        } else {
            *(float4*)&Bs[tid >> 4][(tid & 15) * 4] = b0;
        }
        __syncthreads();
        #pragma unroll
        for (int kk = 0; kk < 16; kk++) {
            float4 av = *(float4*)&As[kk][ty * 4];
            float4 bv = *(float4*)&Bs[kk][tx * 4];
            float a[4] = {av.x, av.y, av.z, av.w};
            float b[4] = {bv.x, bv.y, bv.z, bv.w};
            #pragma unroll
            for (int i = 0; i < 4; i++)
                #pragma unroll
                for (int j = 0; j < 4; j++) acc[i][j] += a[i] * b[j];
        }
    }
    #pragma unroll
    for (int i = 0; i < 4; i++) {
        float* cp = &C[(size_t)(row0 + ty * 4 + i) * ldc + col0 + tx * 4];
        *(float4*)cp = make_float4(acc[i][0], acc[i][1], acc[i][2], acc[i][3]);
    }
}

// ---------------- RMSNorm (in-place), D=1536 ----------------
__global__ __launch_bounds__(256) void rmsnorm_q_kernel(float* __restrict__ x,
                                                        const float* __restrict__ w)
{
    const int row = blockIdx.x;
    float* xr = x + (size_t)row * 1536;
    float ss = 0.f;
    for (int c = threadIdx.x; c < 1536; c += 256) { float v = xr[c]; ss += v * v; }
    #pragma unroll
    for (int off = 1; off < 64; off <<= 1) ss += __shfl_xor(ss, off);
    __shared__ float red[4];
    if ((threadIdx.x & 63) == 0) red[threadIdx.x >> 6] = ss;
    __syncthreads();
    float tot = red[0] + red[1] + red[2] + red[3];
    float sc = rsqrtf(tot / 1536.f + 1e-6f);
    for (int c = threadIdx.x; c < 1536; c += 256) xr[c] = xr[c] * sc * w[c];
}

// ------- RMSNorm over first 512 cols of kv_a (ld 576) + k_pe RoPE -------
__global__ __launch_bounds__(256) void rmsnorm_kv_rope_kernel(
    const float* __restrict__ kv_a, const float* __restrict__ w,
    const int* __restrict__ positions, float* __restrict__ kv_fused)
{
    const int row = blockIdx.x;
    const float* xr = kv_a + (size_t)row * 576;
    float* outr = kv_fused + (size_t)row * 576;
    float ss = 0.f;
    for (int c = threadIdx.x; c < 512; c += 256) { float v = xr[c]; ss += v * v; }
    #pragma unroll
    for (int off = 1; off < 64; off <<= 1) ss += __shfl_xor(ss, off);
    __shared__ float red[4];
    if ((threadIdx.x & 63) == 0) red[threadIdx.x >> 6] = ss;
    __syncthreads();
    float tot = red[0] + red[1] + red[2] + red[3];
    float sc = rsqrtf(tot / 512.f + 1e-6f);
    for (int c = threadIdx.x; c < 512; c += 256) outr[c] = xr[c] * sc * w[c];
    if (threadIdx.x < 32) {
        int i = threadIdx.x;
        float inv = __powf(10000.f, -(float)(2 * i) / 64.f);
        float ang = (float)positions[row] * inv;
        float sn, cs;
        sincosf(ang, &sn, &cs);
        float x1 = xr[512 + 2 * i], x2 = xr[512 + 2 * i + 1];
        outr[512 + 2 * i]     = x1 * cs - x2 * sn;
        outr[512 + 2 * i + 1] = x1 * sn + x2 * cs;
    }
}

// ------- q_pe RoPE: q_full[:, n*192+128 .. +191] -> q_att[:, n*576+512 ..] -------
__global__ __launch_bounds__(256) void rope_q_kernel(
    const float* __restrict__ q_full, const int* __restrict__ positions,
    float* __restrict__ q_att)
{
    const int t = blockIdx.x;
    __shared__ float cs[32], sn[32];
    if (threadIdx.x < 32) {
        int i = threadIdx.x;
        float inv = __powf(10000.f, -(float)(2 * i) / 64.f);
        float ang = (float)positions[t] * inv;
        sincosf(ang, &sn[i], &cs[i]);
    }
    __syncthreads();
    for (int w = threadIdx.x; w < 1024; w += 256) {
        int n = w >> 5, i = w & 31;
        const float* src = q_full + (size_t)t * 6144 + n * 192 + 128;
        float x1 = src[2 * i], x2 = src[2 * i + 1];
        float* o = q_att + (size_t)t * 18432 + n * 576 + 512;
        o[2 * i]     = x1 * cs[i] - x2 * sn[i];
        o[2 * i + 1] = x1 * sn[i] + x2 * cs[i];
    }
}

// ---------------- Flash MLA attention + fused o_v projection ----------------
// block: (q-tile of 16, head). 256 thr = 4 waves; wave w owns q rows w*4..w*4+3.
// lane = kg*16 + sIdx : kg = 144-col dot-split group, sIdx = key in tile.
__global__ __launch_bounds__(256) void mla_attn_kernel(
    const float* __restrict__ q_att, const float* __restrict__ kv_fused,
    const float* __restrict__ kv_b_w, float* __restrict__ o_v)
{
    const int qb = blockIdx.x, n = blockIdx.y;
    const int q0 = qb * 16;
    const int tid = threadIdx.x;
    const int wv = tid >> 6, lane = tid & 63;
    const int sIdx = lane & 15, kg = lane >> 4;

    __shared__ float Qs[16][580];
    __shared__ float Kt[16][580];

    for (int i = tid; i < 16 * 144; i += 256) {
        int r = i / 144, c4 = (i % 144) * 4;
        *(float4*)&Qs[r][c4] =
            *(const float4*)&q_att[(size_t)(q0 + r) * 18432 + n * 576 + c4];
    }

    float o_acc[4][8];
    float m_run[4], l_run[4];
    #pragma unroll
    for (int qi = 0; qi < 4; qi++) {
        m_run[qi] = NEG_BIG; l_run[qi] = 0.f;
        #pragma unroll
        for (int j = 0; j < 8; j++) o_acc[qi][j] = 0.f;
    }

    const int c0 = kg * 144;
    for (int s0 = 0; s0 < q0 + 16; s0 += 16) {
        __syncthreads();
        for (int i = tid; i < 16 * 144; i += 256) {
            int r = i / 144, c4 = (i % 144) * 4;
            *(float4*)&Kt[r][c4] =
                *(const float4*)&kv_fused[(size_t)(s0 + r) * 576 + c4];
        }
        __syncthreads();

        float p4[4] = {0.f, 0.f, 0.f, 0.f};
        for (int cc = 0; cc < 144; cc += 4) {
            float4 kvv = *(const float4*)&Kt[sIdx][c0 + cc];
            #pragma unroll
            for (int qi = 0; qi < 4; qi++) {
                float4 qv = *(const float4*)&Qs[wv * 4 + qi][c0 + cc];
                p4[qi] += qv.x * kvv.x + qv.y * kvv.y + qv.z * kvv.z + qv.w * kvv.w;
            }
        }
        #pragma unroll
        for (int qi = 0; qi < 4; qi++) {
            p4[qi] += __shfl_xor(p4[qi], 16);
            p4[qi] += __shfl_xor(p4[qi], 32);
            p4[qi] *= SCALE_F;
            int qg = q0 + wv * 4 + qi, sg = s0 + sIdx;
            if (sg > qg) p4[qi] = NEG_BIG;
            float tm = p4[qi];
            tm = fmaxf(tm, __shfl_xor(tm, 1));
            tm = fmaxf(tm, __shfl_xor(tm, 2));
            tm = fmaxf(tm, __shfl_xor(tm, 4));
            tm = fmaxf(tm, __shfl_xor(tm, 8));
            float mnew = fmaxf(m_run[qi], tm);
            float corr = __expf(m_run[qi] - mnew);
            float pe = __expf(p4[qi] - mnew);
            float psum = pe;
            psum += __shfl_xor(psum, 1);
            psum += __shfl_xor(psum, 2);
            psum += __shfl_xor(psum, 4);
            psum += __shfl_xor(psum, 8);
            l_run[qi] = l_run[qi] * corr + psum;
            m_run[qi] = mnew;
            p4[qi] = pe;
            #pragma unroll
            for (int j = 0; j < 8; j++) o_acc[qi][j] *= corr;
        }
        // PV: lane owns V cols lane*8..+7 (V = Kt[:, 0:512])
        #pragma unroll
        for (int s = 0; s < 16; s++) {
            float4 v0 = *(const float4*)&Kt[s][lane * 8];
            float4 v1 = *(const float4*)&Kt[s][lane * 8 + 4];
            #pragma unroll
            for (int qi = 0; qi < 4; qi++) {
                float pb = __shfl(p4[qi], s);
                o_acc[qi][0] += pb * v0.x; o_acc[qi][1] += pb * v0.y;
                o_acc[qi][2] += pb * v0.z; o_acc[qi][3] += pb * v0.w;
                o_acc[qi][4] += pb * v1.x; o_acc[qi][5] += pb * v1.y;
                o_acc[qi][6] += pb * v1.z; o_acc[qi][7] += pb * v1.w;
            }
        }
    }

    // stage normalized o_latent into Qs[:, 0:512]
    __syncthreads();
    #pragma unroll
    for (int qi = 0; qi < 4; qi++) {
        float inv_l = 1.f / l_run[qi];
        #pragma unroll
        for (int j = 0; j < 8; j++)
            Qs[wv * 4 + qi][lane * 8 + j] = o_acc[qi][j] * inv_l;
    }
    __syncthreads();

    // fused o_v projection: o_v[t, n*128+v] = sum_r o_latent[r] * w_uv[r][v]
    {
        int q = tid >> 4, vg = tid & 15;
        const float* wvp = kv_b_w + n * 256 + 128 + vg * 8;
        float acc[8] = {0.f, 0.f, 0.f, 0.f, 0.f, 0.f, 0.f, 0.f};
        for (int r = 0; r < 512; r++) {
            float ol = Qs[q][r];
            float4 w0 = *(const float4*)&wvp[(size_t)r * 8192];
            float4 w1 = *(const float4*)&wvp[(size_t)r * 8192 + 4];
            acc[0] += ol * w0.x; acc[1] += ol * w0.y;
            acc[2] += ol * w0.z; acc[3] += ol * w0.w;
            acc[4] += ol * w1.x; acc[5] += ol * w1.y;
            acc[6] += ol * w1.z; acc[7] += ol * w1.w;
        }
        float* op = o_v + (size_t)(q0 + q) * 4096 + n * 128 + vg * 8;
        *(float4*)op = make_float4(acc[0], acc[1], acc[2], acc[3]);
        *(float4*)(op + 4) = make_float4(acc[4], acc[5], acc[6], acc[7]);
    }
}

extern "C" void kernel_launch(void* const* d_in, const int* in_sizes, int n_in,
                              void* d_out, int out_size, void* d_ws, size_t ws_size,
                              hipStream_t stream)
{
    const float* hidden  = (const float*)d_in[0];
    const float* q_a_w   = (const float*)d_in[1];
    const float* q_a_ln  = (const float*)d_in[2];
    const float* q_b_w   = (const float*)d_in[3];
    const float* kv_a_w  = (const float*)d_in[4];
    const float* kv_a_ln = (const float*)d_in[5];
    const float* kv_b_w  = (const float*)d_in[6];
    const float* o_w     = (const float*)d_in[7];
    const int* positions = (const int*)d_in[8];

    float* out = (float*)d_out;
    float* kv_fused = out + (size_t)T_TOK * H_DIM;  // [2048, 576]

    // workspace layout (floats). o_v aliases kv_a/q_a/q_full prefix (dead by then).
    float* ws = (float*)d_ws;
    float* kv_a   = ws;                       // 2048*576    = 1,179,648
    float* q_a    = ws + 1179648;             // 2048*1536   = 3,145,728
    float* q_full = ws + 4325376;             // 2048*6144   = 12,582,912
    float* q_att  = ws + 16908288;            // 2048*18432  = 37,748,736 (end 54,657,024 fl = 218.6 MB)
    float* o_v    = ws;                       // 2048*4096   = 8,388,608

    // 1. q_a = hidden @ q_a_w                      [2048,1536] K=4096
    gemm_f32_128<<<dim3(12, 16), 256, 0, stream>>>(hidden, q_a_w, q_a, 4096, 4096, 1536, 1536);
    // 2. kv_a = hidden @ kv_a_w                    [2048,576]  K=4096
    gemm_f32_64<0><<<dim3(9, 32, 1), 256, 0, stream>>>(hidden, kv_a_w, kv_a, 4096, 4096, 576, 576, 0, 0, 0);
    // 3. q_c = rmsnorm(q_a) in-place
    rmsnorm_q_kernel<<<2048, 256, 0, stream>>>(q_a, q_a_ln);
    // 4. c_kv = rmsnorm(kv_a[:, :512]) -> kv_fused[:, :512]; k_pe rope -> kv_fused[:, 512:]
    rmsnorm_kv_rope_kernel<<<2048, 256, 0, stream>>>(kv_a, kv_a_ln, positions, kv_fused);
    // 5. q_full = q_c @ q_b_w                      [2048,6144] K=1536
    gemm_f32_128<<<dim3(48, 16), 256, 0, stream>>>(q_a, q_b_w, q_full, 1536, 1536, 6144, 6144);
    // 6. ql_nope (batched over heads): q_att[:, n*576 + 0:512] = q_nope_n @ w_uk_n^T
    gemm_f32_64<1><<<dim3(8, 32, 32), 256, 0, stream>>>(q_full, kv_b_w, q_att, 128, 6144, 8192, 18432, 192, 256, 576);
    // 7. q_pe rope -> q_att[:, n*576 + 512:576]
    rope_q_kernel<<<2048, 256, 0, stream>>>(q_full, positions, q_att);
    // 8. flash attention + fused o_v projection -> o_v [2048, 4096]
    mla_attn_kernel<<<dim3(128, 32), 256, 0, stream>>>(q_att, kv_fused, kv_b_w, o_v);
    // 9. output = o_v @ o_w                        [2048,4096] K=4096
    gemm_f32_128<<<dim3(32, 16), 256, 0, stream>>>(o_v, o_w, out, 4096, 4096, 4096, 4096);
}

// Round 3
// 5363.060 us; speedup vs baseline: 1.5705x; 1.5705x over previous
//
#include <hip/hip_runtime.h>
#include <hip/hip_bf16.h>
#include <math.h>

#define T_TOK 2048
#define H_DIM 4096
#define N_HEADS 32
#define SCALE_F 0.07216878364870323f  // 192^-0.5
#define NEG_BIG -1e30f

typedef unsigned short ushort_t;
typedef __attribute__((ext_vector_type(8))) short bfrag8;
typedef __attribute__((ext_vector_type(4))) float f32acc4;

#define MFMA16(A, B, C) __builtin_amdgcn_mfma_f32_16x16x32_bf16(A, B, C, 0, 0, 0)

__device__ __forceinline__ ushort_t f2bf(float x) {
    union { float f; unsigned u; } c; c.f = x;
    unsigned r = c.u + 0x7FFFu + ((c.u >> 16) & 1u);
    return (ushort_t)(r >> 16);
}

// ---------------- 128x128 fp32 GEMM (row-major, C = A@B) ----------------
__global__ __launch_bounds__(256) void gemm_f32_128(
    const float* __restrict__ A, const float* __restrict__ B, float* __restrict__ C,
    int K, int lda, int ldb, int ldc)
{
    __shared__ float As[16][132];
    __shared__ float Bs[16][132];
    const int tid = threadIdx.x;
    const int row0 = blockIdx.y * 128, col0 = blockIdx.x * 128;
    const int tx = tid & 15, ty = tid >> 4;
    const int am = tid >> 2, akq = (tid & 3) * 4;
    const int bk = tid >> 5, bn = (tid & 31) * 4;

    float acc[8][8];
    #pragma unroll
    for (int i = 0; i < 8; i++)
        #pragma unroll
        for (int j = 0; j < 8; j++) acc[i][j] = 0.f;

    for (int k0 = 0; k0 < K; k0 += 16) {
        float4 a0 = *(const float4*)&A[(size_t)(row0 + am) * lda + k0 + akq];
        float4 a1 = *(const float4*)&A[(size_t)(row0 + am + 64) * lda + k0 + akq];
        float4 b0 = *(const float4*)&B[(size_t)(k0 + bk) * ldb + col0 + bn];
        float4 b1 = *(const float4*)&B[(size_t)(k0 + bk + 8) * ldb + col0 + bn];
        __syncthreads();
        As[akq + 0][am] = a0.x; As[akq + 1][am] = a0.y;
        As[akq + 2][am] = a0.z; As[akq + 3][am] = a0.w;
        As[akq + 0][am + 64] = a1.x; As[akq + 1][am + 64] = a1.y;
        As[akq + 2][am + 64] = a1.z; As[akq + 3][am + 64] = a1.w;
        *(float4*)&Bs[bk][bn] = b0;
        *(float4*)&Bs[bk + 8][bn] = b1;
        __syncthreads();
        #pragma unroll
        for (int kk = 0; kk < 16; kk++) {
            float4 av0 = *(float4*)&As[kk][ty * 8];
            float4 av1 = *(float4*)&As[kk][ty * 8 + 4];
            float4 bv0 = *(float4*)&Bs[kk][tx * 8];
            float4 bv1 = *(float4*)&Bs[kk][tx * 8 + 4];
            float a[8] = {av0.x, av0.y, av0.z, av0.w, av1.x, av1.y, av1.z, av1.w};
            float b[8] = {bv0.x, bv0.y, bv0.z, bv0.w, bv1.x, bv1.y, bv1.z, bv1.w};
            #pragma unroll
            for (int i = 0; i < 8; i++)
                #pragma unroll
                for (int j = 0; j < 8; j++) acc[i][j] += a[i] * b[j];
        }
    }
    #pragma unroll
    for (int i = 0; i < 8; i++) {
        float* cp = &C[(size_t)(row0 + ty * 8 + i) * ldc + col0 + tx * 8];
        *(float4*)cp = make_float4(acc[i][0], acc[i][1], acc[i][2], acc[i][3]);
        *(float4*)(cp + 4) = make_float4(acc[i][4], acc[i][5], acc[i][6], acc[i][7]);
    }
}

// ------ 64x64 fp32 GEMM, batched; BT=1 => C = A@B^T; BF16OUT writes bf16 ------
template<int BT, int BF16OUT>
__global__ __launch_bounds__(256) void gemm_f32_64(
    const float* __restrict__ A, const float* __restrict__ B, void* __restrict__ Cv,
    int K, int lda, int ldb, int ldc, long sA, long sB, long sC)
{
    const int bz = blockIdx.z;
    A += (size_t)bz * sA; B += (size_t)bz * sB;
    __shared__ float As[16][68];
    __shared__ float Bs[16][68];
    const int tid = threadIdx.x;
    const int row0 = blockIdx.y * 64, col0 = blockIdx.x * 64;
    const int tx = tid & 15, ty = tid >> 4;
    const int lm = tid >> 2, lkq = (tid & 3) * 4;

    float acc[4][4];
    #pragma unroll
    for (int i = 0; i < 4; i++)
        #pragma unroll
        for (int j = 0; j < 4; j++) acc[i][j] = 0.f;

    for (int k0 = 0; k0 < K; k0 += 16) {
        float4 a0 = *(const float4*)&A[(size_t)(row0 + lm) * lda + k0 + lkq];
        float4 b0;
        if (BT) b0 = *(const float4*)&B[(size_t)(col0 + lm) * ldb + k0 + lkq];
        else    b0 = *(const float4*)&B[(size_t)(k0 + (tid >> 4)) * ldb + col0 + (tid & 15) * 4];
        __syncthreads();
        As[lkq + 0][lm] = a0.x; As[lkq + 1][lm] = a0.y;
        As[lkq + 2][lm] = a0.z; As[lkq + 3][lm] = a0.w;
        if (BT) {
            Bs[lkq + 0][lm] = b0.x; Bs[lkq + 1][lm] = b0.y;
            Bs[lkq + 2][lm] = b0.z; Bs[lkq + 3][lm] = b0.w;
        } else {
            *(float4*)&Bs[tid >> 4][(tid & 15) * 4] = b0;
        }
        __syncthreads();
        #pragma unroll
        for (int kk = 0; kk < 16; kk++) {
            float4 av = *(float4*)&As[kk][ty * 4];
            float4 bv = *(float4*)&Bs[kk][tx * 4];
            float a[4] = {av.x, av.y, av.z, av.w};
            float b[4] = {bv.x, bv.y, bv.z, bv.w};
            #pragma unroll
            for (int i = 0; i < 4; i++)
                #pragma unroll
                for (int j = 0; j < 4; j++) acc[i][j] += a[i] * b[j];
        }
    }
    #pragma unroll
    for (int i = 0; i < 4; i++) {
        if (BF16OUT) {
            ushort_t* cp = (ushort_t*)Cv + (size_t)bz * sC
                         + (size_t)(row0 + ty * 4 + i) * ldc + col0 + tx * 4;
            #pragma unroll
            for (int j = 0; j < 4; j++) cp[j] = f2bf(acc[i][j]);
        } else {
            float* cp = (float*)Cv + (size_t)bz * sC
                      + (size_t)(row0 + ty * 4 + i) * ldc + col0 + tx * 4;
            *(float4*)cp = make_float4(acc[i][0], acc[i][1], acc[i][2], acc[i][3]);
        }
    }
}

// ---------------- RMSNorm (in-place), D=1536 ----------------
__global__ __launch_bounds__(256) void rmsnorm_q_kernel(float* __restrict__ x,
                                                        const float* __restrict__ w)
{
    const int row = blockIdx.x;
    float* xr = x + (size_t)row * 1536;
    float ss = 0.f;
    for (int c = threadIdx.x; c < 1536; c += 256) { float v = xr[c]; ss += v * v; }
    #pragma unroll
    for (int off = 1; off < 64; off <<= 1) ss += __shfl_xor(ss, off);
    __shared__ float red[4];
    if ((threadIdx.x & 63) == 0) red[threadIdx.x >> 6] = ss;
    __syncthreads();
    float tot = red[0] + red[1] + red[2] + red[3];
    float sc = rsqrtf(tot / 1536.f + 1e-6f);
    for (int c = threadIdx.x; c < 1536; c += 256) xr[c] = xr[c] * sc * w[c];
}

// -- RMSNorm over first 512 cols of kv_a (ld 576) + k_pe RoPE; f32 + bf16 out --
__global__ __launch_bounds__(256) void rmsnorm_kv_rope_kernel(
    const float* __restrict__ kv_a, const float* __restrict__ w,
    const int* __restrict__ positions, float* __restrict__ kv_fused,
    ushort_t* __restrict__ kv_bf)
{
    const int row = blockIdx.x;
    const float* xr = kv_a + (size_t)row * 576;
    float* outr = kv_fused + (size_t)row * 576;
    ushort_t* outb = kv_bf + (size_t)row * 576;
    float ss = 0.f;
    for (int c = threadIdx.x; c < 512; c += 256) { float v = xr[c]; ss += v * v; }
    #pragma unroll
    for (int off = 1; off < 64; off <<= 1) ss += __shfl_xor(ss, off);
    __shared__ float red[4];
    if ((threadIdx.x & 63) == 0) red[threadIdx.x >> 6] = ss;
    __syncthreads();
    float tot = red[0] + red[1] + red[2] + red[3];
    float sc = rsqrtf(tot / 512.f + 1e-6f);
    for (int c = threadIdx.x; c < 512; c += 256) {
        float v = xr[c] * sc * w[c];
        outr[c] = v; outb[c] = f2bf(v);
    }
    if (threadIdx.x < 32) {
        int i = threadIdx.x;
        float inv = __powf(10000.f, -(float)(2 * i) / 64.f);
        float ang = (float)positions[row] * inv;
        float sn, cs;
        sincosf(ang, &sn, &cs);
        float x1 = xr[512 + 2 * i], x2 = xr[512 + 2 * i + 1];
        float o0 = x1 * cs - x2 * sn, o1 = x1 * sn + x2 * cs;
        outr[512 + 2 * i] = o0;      outr[512 + 2 * i + 1] = o1;
        outb[512 + 2 * i] = f2bf(o0); outb[512 + 2 * i + 1] = f2bf(o1);
    }
}

// ------- q_pe RoPE -> q_att_bf[:, n*576 + 512 ..], bf16 -------
__global__ __launch_bounds__(256) void rope_q_kernel(
    const float* __restrict__ q_full, const int* __restrict__ positions,
    ushort_t* __restrict__ q_att)
{
    const int t = blockIdx.x;
    __shared__ float cs[32], sn[32];
    if (threadIdx.x < 32) {
        int i = threadIdx.x;
        float inv = __powf(10000.f, -(float)(2 * i) / 64.f);
        float ang = (float)positions[t] * inv;
        sincosf(ang, &sn[i], &cs[i]);
    }
    __syncthreads();
    for (int w = threadIdx.x; w < 1024; w += 256) {
        int n = w >> 5, i = w & 31;
        const float* src = q_full + (size_t)t * 6144 + n * 192 + 128;
        float x1 = src[2 * i], x2 = src[2 * i + 1];
        ushort_t* o = q_att + (size_t)t * 18432 + n * 576 + 512;
        o[2 * i]     = f2bf(x1 * cs[i] - x2 * sn[i]);
        o[2 * i + 1] = f2bf(x1 * sn[i] + x2 * cs[i]);
    }
}

// ------- transpose c_kv: kv_bf[2048][576] (first 512 cols) -> vT[512][2048] -------
__global__ __launch_bounds__(256) void transpose_v_kernel(
    const ushort_t* __restrict__ kv_bf, ushort_t* __restrict__ vT)
{
    __shared__ ushort_t tile[64][65];
    const int s0 = blockIdx.x * 64, r0 = blockIdx.y * 64;
    const int tid = threadIdx.x;
    #pragma unroll
    for (int i = 0; i < 16; i++) {
        int idx = i * 256 + tid;
        int sr = idx >> 6, rc = idx & 63;
        tile[sr][rc] = kv_bf[(size_t)(s0 + sr) * 576 + r0 + rc];
    }
    __syncthreads();
    #pragma unroll
    for (int i = 0; i < 16; i++) {
        int idx = i * 256 + tid;
        int rr = idx >> 6, sc = idx & 63;
        vT[(size_t)(r0 + rr) * 2048 + s0 + sc] = tile[sc][rr];
    }
}

// ---- w_uvT[n][128 v][512 r] bf16 from kv_b_w f32 [512][8192] (cols n*256+128..255) ----
__global__ __launch_bounds__(256) void conv_wuv_kernel(
    const float* __restrict__ kv_b_w, ushort_t* __restrict__ w_uvT)
{
    const int n = blockIdx.x, r0 = blockIdx.y * 64;
    const int tid = threadIdx.x;
    __shared__ ushort_t tl[64][136];
    #pragma unroll
    for (int i = 0; i < 32; i++) {
        int idx = i * 256 + tid;
        int rl = idx >> 7, v = idx & 127;
        tl[rl][v] = f2bf(kv_b_w[(size_t)(r0 + rl) * 8192 + n * 256 + 128 + v]);
    }
    __syncthreads();
    #pragma unroll
    for (int i = 0; i < 32; i++) {
        int idx = i * 256 + tid;
        int v = idx >> 6, rl = idx & 63;
        w_uvT[((size_t)n * 128 + v) * 512 + r0 + rl] = tl[rl][v];
    }
}

// ---------------- MFMA flash MLA attention + fused o_v projection ----------------
// grid (32 qb, 32 n); 4 waves; wave wv owns q rows qwb..qwb+15, fully independent.
__global__ __launch_bounds__(256) void mla_attn_mfma(
    const ushort_t* __restrict__ q_att, const ushort_t* __restrict__ kv_bf,
    const ushort_t* __restrict__ vT_bf, const ushort_t* __restrict__ w_uvT,
    float* __restrict__ o_v)
{
    const int qb = gridDim.x - 1 - blockIdx.x;  // big blocks first
    const int n = blockIdx.y;
    const int q0 = qb * 64;
    const int tid = threadIdx.x;
    const int wv = tid >> 6, lane = tid & 63;
    const int lr = lane & 15, lg = lane >> 4;
    const int qwb = q0 + wv * 16;

    __shared__ ushort_t smem[4][16 * 520];
    ushort_t* mylds = &smem[wv][0];

    // Q fragments (A-layout): row = lr, k-chunk c covers d = c*32 + lg*8 + j
    bfrag8 qf[18];
    const ushort_t* qrow = q_att + (size_t)(qwb + lr) * 18432 + n * 576 + lg * 8;
    #pragma unroll
    for (int c = 0; c < 18; c++) qf[c] = *(const bfrag8*)(qrow + c * 32);

    f32acc4 O[32];
    #pragma unroll
    for (int i = 0; i < 32; i++) O[i] = (f32acc4){0.f, 0.f, 0.f, 0.f};
    float m_run[4] = {NEG_BIG, NEG_BIG, NEG_BIG, NEG_BIG};
    float l_run[4] = {0.f, 0.f, 0.f, 0.f};

    const int ntiles = (qwb + 16 + 31) >> 5;
    for (int t = 0; t < ntiles; t++) {
        const int s0 = t * 32;
        // ---- QK^T: S[16q][32s] as two 16-col accs
        f32acc4 sA = {0,0,0,0}, sB = {0,0,0,0};
        const ushort_t* kbase = kv_bf + (size_t)(s0 + lr) * 576 + lg * 8;
        #pragma unroll
        for (int c = 0; c < 18; c++) {
            bfrag8 k0 = *(const bfrag8*)(kbase + c * 32);
            bfrag8 k1 = *(const bfrag8*)(kbase + 16 * 576 + c * 32);
            sA = MFMA16(qf[c], k0, sA);
            sB = MFMA16(qf[c], k1, sB);
        }
        // ---- online softmax; D rows q = lg*4+r, cols s0+lr (sA) / s0+16+lr (sB)
        float corr_s[4];
        #pragma unroll
        for (int r = 0; r < 4; r++) {
            float v0 = sA[r] * SCALE_F, v1 = sB[r] * SCALE_F;
            int qg = qwb + (lg << 2) + r;
            if (s0 + lr > qg) v0 = NEG_BIG;
            if (s0 + 16 + lr > qg) v1 = NEG_BIG;
            float tm = fmaxf(v0, v1);
            tm = fmaxf(tm, __shfl_xor(tm, 1));
            tm = fmaxf(tm, __shfl_xor(tm, 2));
            tm = fmaxf(tm, __shfl_xor(tm, 4));
            tm = fmaxf(tm, __shfl_xor(tm, 8));
            float mnew = fmaxf(m_run[r], tm);
            float corr = __expf(m_run[r] - mnew);
            float p0 = __expf(v0 - mnew);
            float p1 = __expf(v1 - mnew);
            float ps = p0 + p1;
            ps += __shfl_xor(ps, 1);
            ps += __shfl_xor(ps, 2);
            ps += __shfl_xor(ps, 4);
            ps += __shfl_xor(ps, 8);
            l_run[r] = l_run[r] * corr + ps;
            m_run[r] = mnew;
            corr_s[r] = corr;
            int pidx = ((lg << 2) + r) * 32 + lr;
            mylds[pidx] = f2bf(p0);
            mylds[pidx + 16] = f2bf(p1);
        }
        #pragma unroll
        for (int i = 0; i < 32; i++) {
            O[i][0] *= corr_s[0]; O[i][1] *= corr_s[1];
            O[i][2] *= corr_s[2]; O[i][3] *= corr_s[3];
        }
        // ---- PV: O[16q][512r] += P[16][32] @ V[32][512]; B-frags from vT
        bfrag8 pf = *(const bfrag8*)(mylds + lr * 32 + lg * 8);
        const ushort_t* vbase = vT_bf + (size_t)lr * 2048 + s0 + lg * 8;
        #pragma unroll
        for (int rb = 0; rb < 32; rb++) {
            bfrag8 vf = *(const bfrag8*)(vbase + (size_t)rb * 16 * 2048);
            O[rb] = MFMA16(pf, vf, O[rb]);
        }
    }

    // ---- normalize + stage o_latent bf16 in LDS [16 q][520 pad]
    float inv_l[4];
    #pragma unroll
    for (int r = 0; r < 4; r++) inv_l[r] = 1.f / l_run[r];
    #pragma unroll
    for (int rb = 0; rb < 32; rb++) {
        #pragma unroll
        for (int r = 0; r < 4; r++) {
            int q = (lg << 2) + r;
            mylds[q * 520 + rb * 16 + lr] = f2bf(O[rb][r] * inv_l[r]);
        }
    }
    // ---- o_v[q][n*128+v] = o_latent @ w_uv : D[v][q] via A=w_uvT, B=o_latent^T
    f32acc4 acc2[8];
    #pragma unroll
    for (int vb = 0; vb < 8; vb++) acc2[vb] = (f32acc4){0.f, 0.f, 0.f, 0.f};
    const ushort_t* wbase = w_uvT + ((size_t)n * 128 + lr) * 512 + lg * 8;
    #pragma unroll
    for (int rc = 0; rc < 16; rc++) {
        bfrag8 bfm = *(const bfrag8*)(mylds + lr * 520 + rc * 32 + lg * 8);
        #pragma unroll
        for (int vb = 0; vb < 8; vb++) {
            bfrag8 af = *(const bfrag8*)(wbase + vb * (16 * 512) + rc * 32);
            acc2[vb] = MFMA16(af, bfm, acc2[vb]);
        }
    }
    #pragma unroll
    for (int vb = 0; vb < 8; vb++)
        #pragma unroll
        for (int r = 0; r < 4; r++)
            o_v[(size_t)(qwb + lr) * 4096 + n * 128 + vb * 16 + (lg << 2) + r] = acc2[vb][r];
}

extern "C" void kernel_launch(void* const* d_in, const int* in_sizes, int n_in,
                              void* d_out, int out_size, void* d_ws, size_t ws_size,
                              hipStream_t stream)
{
    const float* hidden  = (const float*)d_in[0];
    const float* q_a_w   = (const float*)d_in[1];
    const float* q_a_ln  = (const float*)d_in[2];
    const float* q_b_w   = (const float*)d_in[3];
    const float* kv_a_w  = (const float*)d_in[4];
    const float* kv_a_ln = (const float*)d_in[5];
    const float* kv_b_w  = (const float*)d_in[6];
    const float* o_w     = (const float*)d_in[7];
    const int* positions = (const int*)d_in[8];

    float* out = (float*)d_out;
    float* kv_fused = out + (size_t)T_TOK * H_DIM;  // [2048, 576] f32

    // workspace layout (float offsets)
    float* ws = (float*)d_ws;
    float* kv_a     = ws;                              // 1,179,648 f
    float* q_a      = ws + 1179648;                    // 3,145,728 f
    float* q_full   = ws + 4325376;                    // 12,582,912 f
    ushort_t* q_att_bf = (ushort_t*)(ws + 16908288);   // 37,748,736 hw
    ushort_t* kv_bf    = (ushort_t*)(ws + 35782656);   // 1,179,648 hw
    ushort_t* vT_bf    = (ushort_t*)(ws + 36372480);   // 1,048,576 hw
    ushort_t* w_uvT    = (ushort_t*)(ws + 36896768);   // 2,097,152 hw (end 37,945,344 f)
    float* o_v      = ws;                              // 8,388,608 f (aliases kv_a/q_a/q_full[:])

    // 1. q_a = hidden @ q_a_w                      [2048,1536] K=4096
    gemm_f32_128<<<dim3(12, 16), 256, 0, stream>>>(hidden, q_a_w, q_a, 4096, 4096, 1536, 1536);
    // 2. kv_a = hidden @ kv_a_w                    [2048,576]  K=4096
    gemm_f32_64<0,0><<<dim3(9, 32, 1), 256, 0, stream>>>(hidden, kv_a_w, kv_a, 4096, 4096, 576, 576, 0, 0, 0);
    // 3. q_c = rmsnorm(q_a) in-place
    rmsnorm_q_kernel<<<2048, 256, 0, stream>>>(q_a, q_a_ln);
    // 4. kv_fused f32 (output) + kv_bf bf16
    rmsnorm_kv_rope_kernel<<<2048, 256, 0, stream>>>(kv_a, kv_a_ln, positions, kv_fused, kv_bf);
    // 5. vT_bf = c_kv^T bf16 [512][2048]
    transpose_v_kernel<<<dim3(32, 8), 256, 0, stream>>>(kv_bf, vT_bf);
    // 6. w_uvT bf16 [32][128][512]
    conv_wuv_kernel<<<dim3(32, 8), 256, 0, stream>>>(kv_b_w, w_uvT);
    // 7. q_full = q_c @ q_b_w                      [2048,6144] K=1536
    gemm_f32_128<<<dim3(48, 16), 256, 0, stream>>>(q_a, q_b_w, q_full, 1536, 1536, 6144, 6144);
    // 8. ql_nope -> q_att_bf[:, n*576+0:512] (bf16), batched over heads
    gemm_f32_64<1,1><<<dim3(8, 32, 32), 256, 0, stream>>>(q_full, kv_b_w, q_att_bf, 128, 6144, 8192, 18432, 192, 256, 576);
    // 9. q_pe rope -> q_att_bf[:, n*576+512:576] (bf16)
    rope_q_kernel<<<2048, 256, 0, stream>>>(q_full, positions, q_att_bf);
    // 10. MFMA flash attention + fused o_v projection -> o_v f32 [2048,4096]
    mla_attn_mfma<<<dim3(32, 32), 256, 0, stream>>>(q_att_bf, kv_bf, vT_bf, w_uvT, o_v);
    // 11. output = o_v @ o_w                       [2048,4096] K=4096
    gemm_f32_128<<<dim3(32, 16), 256, 0, stream>>>(o_v, o_w, out, 4096, 4096, 4096, 4096);
}

// Round 4
// 2499.520 us; speedup vs baseline: 3.3697x; 2.1456x over previous
//
#include <hip/hip_runtime.h>
#include <hip/hip_bf16.h>
#include <math.h>

#define T_TOK 2048
#define H_DIM 4096
#define N_HEADS 32
#define SCALE_F 0.07216878364870323f  // 192^-0.5
#define NEG_BIG -1e30f

typedef unsigned short ushort_t;
typedef __attribute__((ext_vector_type(8))) short bfrag8;
typedef __attribute__((ext_vector_type(4))) float f32acc4;

#define MFMA16(A, B, C) __builtin_amdgcn_mfma_f32_16x16x32_bf16(A, B, C, 0, 0, 0)

#define GLDS16(g, l) __builtin_amdgcn_global_load_lds( \
    (const __attribute__((address_space(1))) void*)(g), \
    (__attribute__((address_space(3))) void*)(l), 16, 0, 0)

__device__ __forceinline__ ushort_t f2bf(float x) {
    union { float f; unsigned u; } c; c.f = x;
    unsigned r = c.u + 0x7FFFu + ((c.u >> 16) & 1u);
    return (ushort_t)(r >> 16);
}
__device__ __forceinline__ float bfu2f(ushort_t u) {
    union { unsigned u; float f; } c; c.u = ((unsigned)u) << 16; return c.f;
}

// ---------- elementwise f32 -> bf16 (float4 granularity) ----------
__global__ __launch_bounds__(256) void conv_f32_bf16(
    const float* __restrict__ x, ushort_t* __restrict__ y, int n4)
{
    int i = blockIdx.x * 256 + threadIdx.x;
    int stride = gridDim.x * 256;
    for (; i < n4; i += stride) {
        float4 v = ((const float4*)x)[i];
        ushort4 o;
        o.x = f2bf(v.x); o.y = f2bf(v.y); o.z = f2bf(v.z); o.w = f2bf(v.w);
        ((ushort4*)y)[i] = o;
    }
}

// ---------- transpose+convert: W f32 [K][N] -> WT bf16 [N][K] (64|K, 64|N) ----------
__global__ __launch_bounds__(256) void transpose_conv(
    const float* __restrict__ W, ushort_t* __restrict__ WT, int K, int N)
{
    __shared__ ushort_t tl[64][72];
    const int k0 = blockIdx.x * 64, n0 = blockIdx.y * 64;
    const int tid = threadIdx.x;
    #pragma unroll
    for (int i = 0; i < 16; i++) {
        int idx = i * 256 + tid;
        int kr = idx >> 6, nc = idx & 63;
        tl[kr][nc] = f2bf(W[(size_t)(k0 + kr) * N + n0 + nc]);
    }
    __syncthreads();
    #pragma unroll
    for (int i = 0; i < 16; i++) {
        int idx = i * 256 + tid;
        int nr = idx >> 6, kc = idx & 63;
        WT[(size_t)(n0 + nr) * K + k0 + kc] = tl[kc][nr];
    }
}

// ---------- w_ukb[n][r][d] bf16 = kv_b_w[r][n*256+d] ----------
__global__ __launch_bounds__(256) void conv_wuk(
    const float* __restrict__ kv_b_w, ushort_t* __restrict__ w_ukb)
{
    int idx = blockIdx.x * 256 + threadIdx.x;   // 0 .. 2097151
    int n = idx >> 16, rem = idx & 65535;
    int r = rem >> 7, d = rem & 127;
    w_ukb[idx] = f2bf(kv_b_w[(size_t)r * 8192 + n * 256 + d]);
}

// ---- w_uvT[n][128 v][512 r] bf16 from kv_b_w f32 [512][8192] (cols n*256+128..255) ----
__global__ __launch_bounds__(256) void conv_wuv_kernel(
    const float* __restrict__ kv_b_w, ushort_t* __restrict__ w_uvT)
{
    const int n = blockIdx.x, r0 = blockIdx.y * 64;
    const int tid = threadIdx.x;
    __shared__ ushort_t tl[64][136];
    #pragma unroll
    for (int i = 0; i < 32; i++) {
        int idx = i * 256 + tid;
        int rl = idx >> 7, v = idx & 127;
        tl[rl][v] = f2bf(kv_b_w[(size_t)(r0 + rl) * 8192 + n * 256 + 128 + v]);
    }
    __syncthreads();
    #pragma unroll
    for (int i = 0; i < 32; i++) {
        int idx = i * 256 + tid;
        int v = idx >> 6, rl = idx & 63;
        w_uvT[((size_t)n * 128 + v) * 512 + r0 + rl] = tl[rl][v];
    }
}

// ---------------- bf16 MFMA GEMM: C[M,N] = A[M,K] @ BT[N,K]^T ----------------
// 128x128 tile, BK=32, 4 waves (2x2), global_load_lds staging, N-guarded.
template<int BF16OUT>
__global__ __launch_bounds__(256) void gemm_bf16_128(
    const ushort_t* __restrict__ A, const ushort_t* __restrict__ BT, void* __restrict__ Cv,
    int K, int N, int lda, int ldb, int ldc, long sA, long sB, long sC)
{
    const int bz = blockIdx.z;
    A  += (size_t)bz * sA;
    BT += (size_t)bz * sB;
    const int tid = threadIdx.x;
    const int wv = tid >> 6, lane = tid & 63;
    const int lr = lane & 15, lg = lane >> 4;
    const int wr = wv >> 1, wc = wv & 1;
    const int row0 = blockIdx.y * 128, col0 = blockIdx.x * 128;

    __shared__ ushort_t As[128 * 32];
    __shared__ ushort_t Bs[128 * 32];

    f32acc4 acc[4][4];
    #pragma unroll
    for (int i = 0; i < 4; i++)
        #pragma unroll
        for (int j = 0; j < 4; j++) acc[i][j] = (f32acc4){0.f, 0.f, 0.f, 0.f};

    for (int k0 = 0; k0 < K; k0 += 32) {
        __syncthreads();
        #pragma unroll
        for (int it = 0; it < 2; it++) {
            int slot = it * 256 + wv * 64 + lane;
            int row = slot >> 2, part = slot & 3;
            const ushort_t* ga = A + (size_t)(row0 + row) * lda + k0 + part * 8;
            GLDS16(ga, &As[(it * 256 + wv * 64) * 8]);
        }
        #pragma unroll
        for (int it = 0; it < 2; it++) {
            int slot = it * 256 + wv * 64 + lane;
            int row = slot >> 2, part = slot & 3;
            int brow = col0 + row; if (brow > N - 1) brow = N - 1;
            const ushort_t* gb = BT + (size_t)brow * ldb + k0 + part * 8;
            GLDS16(gb, &Bs[(it * 256 + wv * 64) * 8]);
        }
        __syncthreads();
        bfrag8 af[4], bf[4];
        #pragma unroll
        for (int i = 0; i < 4; i++) {
            af[i] = *(const bfrag8*)&As[(wr * 64 + i * 16 + lr) * 32 + lg * 8];
            bf[i] = *(const bfrag8*)&Bs[(wc * 64 + i * 16 + lr) * 32 + lg * 8];
        }
        #pragma unroll
        for (int i = 0; i < 4; i++)
            #pragma unroll
            for (int j = 0; j < 4; j++)
                acc[i][j] = MFMA16(af[i], bf[j], acc[i][j]);
    }

    ushort_t* Cb = (ushort_t*)Cv + (size_t)bz * sC;
    float*    Cf = (float*)Cv + (size_t)bz * sC;
    #pragma unroll
    for (int i = 0; i < 4; i++) {
        #pragma unroll
        for (int j = 0; j < 4; j++) {
            int col = col0 + wc * 64 + j * 16 + lr;
            if (col < N) {
                #pragma unroll
                for (int r = 0; r < 4; r++) {
                    int row = row0 + wr * 64 + i * 16 + (lg << 2) + r;
                    if (BF16OUT) Cb[(size_t)row * ldc + col] = f2bf(acc[i][j][r]);
                    else         Cf[(size_t)row * ldc + col] = acc[i][j][r];
                }
            }
        }
    }
}

// ---------------- RMSNorm D=1536: q_a f32 -> q_c bf16 ----------------
__global__ __launch_bounds__(256) void rmsnorm_q_kernel(
    const float* __restrict__ x, const float* __restrict__ w, ushort_t* __restrict__ qc)
{
    const int row = blockIdx.x;
    const float* xr = x + (size_t)row * 1536;
    ushort_t* outr = qc + (size_t)row * 1536;
    float ss = 0.f;
    for (int c = threadIdx.x; c < 1536; c += 256) { float v = xr[c]; ss += v * v; }
    #pragma unroll
    for (int off = 1; off < 64; off <<= 1) ss += __shfl_xor(ss, off);
    __shared__ float red[4];
    if ((threadIdx.x & 63) == 0) red[threadIdx.x >> 6] = ss;
    __syncthreads();
    float tot = red[0] + red[1] + red[2] + red[3];
    float sc = rsqrtf(tot / 1536.f + 1e-6f);
    for (int c = threadIdx.x; c < 1536; c += 256) outr[c] = f2bf(xr[c] * sc * w[c]);
}

// -- RMSNorm over first 512 cols of kv_a (ld 576) + k_pe RoPE; f32 + bf16 out --
__global__ __launch_bounds__(256) void rmsnorm_kv_rope_kernel(
    const float* __restrict__ kv_a, const float* __restrict__ w,
    const int* __restrict__ positions, float* __restrict__ kv_fused,
    ushort_t* __restrict__ kv_bf)
{
    const int row = blockIdx.x;
    const float* xr = kv_a + (size_t)row * 576;
    float* outr = kv_fused + (size_t)row * 576;
    ushort_t* outb = kv_bf + (size_t)row * 576;
    float ss = 0.f;
    for (int c = threadIdx.x; c < 512; c += 256) { float v = xr[c]; ss += v * v; }
    #pragma unroll
    for (int off = 1; off < 64; off <<= 1) ss += __shfl_xor(ss, off);
    __shared__ float red[4];
    if ((threadIdx.x & 63) == 0) red[threadIdx.x >> 6] = ss;
    __syncthreads();
    float tot = red[0] + red[1] + red[2] + red[3];
    float sc = rsqrtf(tot / 512.f + 1e-6f);
    for (int c = threadIdx.x; c < 512; c += 256) {
        float v = xr[c] * sc * w[c];
        outr[c] = v; outb[c] = f2bf(v);
    }
    if (threadIdx.x < 32) {
        int i = threadIdx.x;
        float inv = __powf(10000.f, -(float)(2 * i) / 64.f);
        float ang = (float)positions[row] * inv;
        float sn, cs;
        sincosf(ang, &sn, &cs);
        float x1 = xr[512 + 2 * i], x2 = xr[512 + 2 * i + 1];
        float o0 = x1 * cs - x2 * sn, o1 = x1 * sn + x2 * cs;
        outr[512 + 2 * i] = o0;       outr[512 + 2 * i + 1] = o1;
        outb[512 + 2 * i] = f2bf(o0); outb[512 + 2 * i + 1] = f2bf(o1);
    }
}

// ------- q_pe RoPE: q_full bf16 -> q_att_bf[:, n*576 + 512..] -------
__global__ __launch_bounds__(256) void rope_q_kernel(
    const ushort_t* __restrict__ q_full, const int* __restrict__ positions,
    ushort_t* __restrict__ q_att)
{
    const int t = blockIdx.x;
    __shared__ float cs[32], sn[32];
    if (threadIdx.x < 32) {
        int i = threadIdx.x;
        float inv = __powf(10000.f, -(float)(2 * i) / 64.f);
        float ang = (float)positions[t] * inv;
        sincosf(ang, &sn[i], &cs[i]);
    }
    __syncthreads();
    for (int w = threadIdx.x; w < 1024; w += 256) {
        int n = w >> 5, i = w & 31;
        const ushort_t* src = q_full + (size_t)t * 6144 + n * 192 + 128;
        float x1 = bfu2f(src[2 * i]), x2 = bfu2f(src[2 * i + 1]);
        ushort_t* o = q_att + (size_t)t * 18432 + n * 576 + 512;
        o[2 * i]     = f2bf(x1 * cs[i] - x2 * sn[i]);
        o[2 * i + 1] = f2bf(x1 * sn[i] + x2 * cs[i]);
    }
}

// ------- transpose c_kv: kv_bf[2048][576] (first 512 cols) -> vT[512][2048] -------
__global__ __launch_bounds__(256) void transpose_v_kernel(
    const ushort_t* __restrict__ kv_bf, ushort_t* __restrict__ vT)
{
    __shared__ ushort_t tile[64][65];
    const int s0 = blockIdx.x * 64, r0 = blockIdx.y * 64;
    const int tid = threadIdx.x;
    #pragma unroll
    for (int i = 0; i < 16; i++) {
        int idx = i * 256 + tid;
        int sr = idx >> 6, rc = idx & 63;
        tile[sr][rc] = kv_bf[(size_t)(s0 + sr) * 576 + r0 + rc];
    }
    __syncthreads();
    #pragma unroll
    for (int i = 0; i < 16; i++) {
        int idx = i * 256 + tid;
        int rr = idx >> 6, sc = idx & 63;
        vT[(size_t)(r0 + rr) * 2048 + s0 + sc] = tile[sc][rr];
    }
}

// ---------------- MFMA flash MLA attention + fused o_v projection ----------------
// grid (64, 8). Block = 16 q-tokens x 4 heads (wave = head). Processes paired
// q-tiles {pa, 127-pa} sequentially -> all blocks equal work (~65 K-tiles).
// K-tile (32 keys x 576) staged in LDS, shared by the 4 waves. V-frags from vT (L2).
__global__ __launch_bounds__(256) void mla_attn_mfma(
    const ushort_t* __restrict__ q_att, const ushort_t* __restrict__ kv_bf,
    const ushort_t* __restrict__ vT_bf, const ushort_t* __restrict__ w_uvT,
    ushort_t* __restrict__ o_v)
{
    const int pa = blockIdx.x;
    const int tid = threadIdx.x;
    const int wv = tid >> 6, lane = tid & 63;
    const int lr = lane & 15, lg = lane >> 4;
    const int n = blockIdx.y * 4 + wv;

    // main: Ks [32][584] @0 (18688 hw) + P [4][512] @18688  (41.5 KB)
    // epilogue: olat [4][16*520] @0                          (66.5 KB)
    __shared__ ushort_t sm[33280];
    ushort_t* Ks = sm;
    ushort_t* Pm = sm + 18688 + wv * 512;

    #pragma unroll 1
    for (int half = 0; half < 2; half++) {
        const int qt = half ? (127 - pa) : pa;
        const int q0 = qt * 16;

        bfrag8 qf[18];
        const ushort_t* qrow = q_att + (size_t)(q0 + lr) * 18432 + n * 576 + lg * 8;
        #pragma unroll
        for (int c = 0; c < 18; c++) qf[c] = *(const bfrag8*)(qrow + c * 32);

        f32acc4 O[32];
        #pragma unroll
        for (int i = 0; i < 32; i++) O[i] = (f32acc4){0.f, 0.f, 0.f, 0.f};
        float m_run[4] = {NEG_BIG, NEG_BIG, NEG_BIG, NEG_BIG};
        float l_run[4] = {0.f, 0.f, 0.f, 0.f};

        const int ntiles = (q0 + 47) >> 5;
        for (int t = 0; t < ntiles; t++) {
            const int s0 = t * 32;
            __syncthreads();
            for (int i = tid; i < 2304; i += 256) {
                int s = i / 72, dq = (i % 72) * 8;
                *(float4*)&Ks[s * 584 + dq] =
                    *(const float4*)&kv_bf[(size_t)(s0 + s) * 576 + dq];
            }
            __syncthreads();

            f32acc4 sA = {0.f, 0.f, 0.f, 0.f}, sB = {0.f, 0.f, 0.f, 0.f};
            #pragma unroll
            for (int c = 0; c < 18; c++) {
                bfrag8 k0 = *(const bfrag8*)&Ks[lr * 584 + c * 32 + lg * 8];
                bfrag8 k1 = *(const bfrag8*)&Ks[(lr + 16) * 584 + c * 32 + lg * 8];
                sA = MFMA16(qf[c], k0, sA);
                sB = MFMA16(qf[c], k1, sB);
            }

            float corr_s[4];
            #pragma unroll
            for (int r = 0; r < 4; r++) {
                float v0 = sA[r] * SCALE_F, v1 = sB[r] * SCALE_F;
                int qg = q0 + (lg << 2) + r;
                if (s0 + lr > qg) v0 = NEG_BIG;
                if (s0 + 16 + lr > qg) v1 = NEG_BIG;
                float tm = fmaxf(v0, v1);
                tm = fmaxf(tm, __shfl_xor(tm, 1));
                tm = fmaxf(tm, __shfl_xor(tm, 2));
                tm = fmaxf(tm, __shfl_xor(tm, 4));
                tm = fmaxf(tm, __shfl_xor(tm, 8));
                float mnew = fmaxf(m_run[r], tm);
                float corr = __expf(m_run[r] - mnew);
                float p0 = __expf(v0 - mnew);
                float p1 = __expf(v1 - mnew);
                float ps = p0 + p1;
                ps += __shfl_xor(ps, 1);
                ps += __shfl_xor(ps, 2);
                ps += __shfl_xor(ps, 4);
                ps += __shfl_xor(ps, 8);
                l_run[r] = l_run[r] * corr + ps;
                m_run[r] = mnew;
                corr_s[r] = corr;
                int pidx = ((lg << 2) + r) * 32 + lr;
                Pm[pidx] = f2bf(p0);
                Pm[pidx + 16] = f2bf(p1);
            }
            #pragma unroll
            for (int i = 0; i < 32; i++) {
                O[i][0] *= corr_s[0]; O[i][1] *= corr_s[1];
                O[i][2] *= corr_s[2]; O[i][3] *= corr_s[3];
            }

            bfrag8 pf = *(const bfrag8*)&Pm[lr * 32 + lg * 8];
            const ushort_t* vbase = vT_bf + (size_t)lr * 2048 + s0 + lg * 8;
            #pragma unroll
            for (int rb = 0; rb < 32; rb++) {
                bfrag8 vf = *(const bfrag8*)(vbase + (size_t)rb * 32768);
                O[rb] = MFMA16(pf, vf, O[rb]);
            }
        }

        // ---- epilogue: normalize, stage o_latent, project through w_uv ----
        __syncthreads();
        float inv_l[4];
        #pragma unroll
        for (int r = 0; r < 4; r++) inv_l[r] = 1.f / l_run[r];
        ushort_t* ol = sm + wv * 8320;
        #pragma unroll
        for (int rb = 0; rb < 32; rb++) {
            #pragma unroll
            for (int r = 0; r < 4; r++) {
                int q = (lg << 2) + r;
                ol[q * 520 + rb * 16 + lr] = f2bf(O[rb][r] * inv_l[r]);
            }
        }
        f32acc4 acc2[8];
        #pragma unroll
        for (int vb = 0; vb < 8; vb++) acc2[vb] = (f32acc4){0.f, 0.f, 0.f, 0.f};
        const ushort_t* wbase = w_uvT + ((size_t)n * 128 + lr) * 512 + lg * 8;
        #pragma unroll
        for (int rc = 0; rc < 16; rc++) {
            bfrag8 bfm = *(const bfrag8*)&ol[lr * 520 + rc * 32 + lg * 8];
            #pragma unroll
            for (int vb = 0; vb < 8; vb++) {
                bfrag8 af = *(const bfrag8*)(wbase + vb * 8192 + rc * 32);
                acc2[vb] = MFMA16(af, bfm, acc2[vb]);
            }
        }
        #pragma unroll
        for (int vb = 0; vb < 8; vb++) {
            ushort4 pk;
            pk.x = f2bf(acc2[vb][0]); pk.y = f2bf(acc2[vb][1]);
            pk.z = f2bf(acc2[vb][2]); pk.w = f2bf(acc2[vb][3]);
            *(ushort4*)&o_v[(size_t)(q0 + lr) * 4096 + n * 128 + vb * 16 + (lg << 2)] = pk;
        }
    }
}

extern "C" void kernel_launch(void* const* d_in, const int* in_sizes, int n_in,
                              void* d_out, int out_size, void* d_ws, size_t ws_size,
                              hipStream_t stream)
{
    const float* hidden  = (const float*)d_in[0];
    const float* q_a_w   = (const float*)d_in[1];
    const float* q_a_ln  = (const float*)d_in[2];
    const float* q_b_w   = (const float*)d_in[3];
    const float* kv_a_w  = (const float*)d_in[4];
    const float* kv_a_ln = (const float*)d_in[5];
    const float* kv_b_w  = (const float*)d_in[6];
    const float* o_w     = (const float*)d_in[7];
    const int* positions = (const int*)d_in[8];

    float* out = (float*)d_out;
    float* kv_fused = out + (size_t)T_TOK * H_DIM;  // [2048, 576] f32

    // ---- workspace layout (float offsets), total 51,707,904 f = 206.8 MB ----
    float* ws = (float*)d_ws;
    float*    kv_a      = ws;                              // 1,179,648 f
    float*    q_a       = ws + 1179648;                    // 3,145,728 f
    ushort_t* o_v_bf    = (ushort_t*)ws;                   // 8,388,608 hw (aliases kv_a+q_a, used later)
    ushort_t* q_c       = (ushort_t*)(ws + 4325376);       // 3,145,728 hw
    ushort_t* hidden_bf = (ushort_t*)(ws + 5898240);       // 8,388,608 hw (dead before q_full written)
    ushort_t* q_full    = (ushort_t*)(ws + 5898240);       // 12,582,912 hw (same region)
    ushort_t* q_att_bf  = (ushort_t*)(ws + 12189696);      // 37,748,736 hw
    ushort_t* kv_bf     = (ushort_t*)(ws + 31064064);      // 1,179,648 hw
    ushort_t* vT_bf     = (ushort_t*)(ws + 31653888);      // 1,048,576 hw
    ushort_t* w_uvT     = (ushort_t*)(ws + 32178176);      // 2,097,152 hw
    ushort_t* w_ukb     = (ushort_t*)(ws + 33226752);      // 2,097,152 hw
    ushort_t* w_qaT     = (ushort_t*)(ws + 34275328);      // 6,291,456 hw
    ushort_t* w_kvaT    = (ushort_t*)(ws + 37421056);      // 2,359,296 hw
    ushort_t* w_qbT     = (ushort_t*)(ws + 38600704);      // 9,437,184 hw
    ushort_t* w_oT      = (ushort_t*)(ws + 43319296);      // 16,777,216 hw

    // ---- weight / input conversions ----
    conv_f32_bf16<<<2048, 256, 0, stream>>>(hidden, hidden_bf, 2097152);
    transpose_conv<<<dim3(64, 24), 256, 0, stream>>>(q_a_w, w_qaT, 4096, 1536);
    transpose_conv<<<dim3(64, 9), 256, 0, stream>>>(kv_a_w, w_kvaT, 4096, 576);
    transpose_conv<<<dim3(24, 96), 256, 0, stream>>>(q_b_w, w_qbT, 1536, 6144);
    transpose_conv<<<dim3(64, 64), 256, 0, stream>>>(o_w, w_oT, 4096, 4096);
    conv_wuk<<<8192, 256, 0, stream>>>(kv_b_w, w_ukb);
    conv_wuv_kernel<<<dim3(32, 8), 256, 0, stream>>>(kv_b_w, w_uvT);

    // ---- projections ----
    // q_a = hidden @ q_a_w   [2048,1536] K=4096, f32 out
    gemm_bf16_128<0><<<dim3(12, 16, 1), 256, 0, stream>>>(
        hidden_bf, w_qaT, q_a, 4096, 1536, 4096, 4096, 1536, 0, 0, 0);
    // kv_a = hidden @ kv_a_w [2048,576] K=4096, f32 out (N-guard)
    gemm_bf16_128<0><<<dim3(5, 16, 1), 256, 0, stream>>>(
        hidden_bf, w_kvaT, kv_a, 4096, 576, 4096, 4096, 576, 0, 0, 0);
    // q_c = rmsnorm(q_a) -> bf16
    rmsnorm_q_kernel<<<2048, 256, 0, stream>>>(q_a, q_a_ln, q_c);
    // kv_fused f32 (output) + kv_bf bf16
    rmsnorm_kv_rope_kernel<<<2048, 256, 0, stream>>>(kv_a, kv_a_ln, positions, kv_fused, kv_bf);
    // vT_bf = c_kv^T bf16 [512][2048]
    transpose_v_kernel<<<dim3(32, 8), 256, 0, stream>>>(kv_bf, vT_bf);
    // q_full = q_c @ q_b_w   [2048,6144] K=1536, bf16 out (overwrites hidden_bf region)
    gemm_bf16_128<1><<<dim3(48, 16, 1), 256, 0, stream>>>(
        q_c, w_qbT, q_full, 1536, 6144, 1536, 1536, 6144, 0, 0, 0);
    // ql_nope (batched over heads): q_att[:, n*576+0:512] = q_nope_n @ w_uk_n^T, bf16 out
    gemm_bf16_128<1><<<dim3(4, 16, 32), 256, 0, stream>>>(
        q_full, w_ukb, q_att_bf, 128, 512, 6144, 128, 18432, 192, 65536, 576);
    // q_pe rope -> q_att[:, n*576+512:576]
    rope_q_kernel<<<2048, 256, 0, stream>>>(q_full, positions, q_att_bf);
    // flash attention + fused o_v projection -> o_v bf16 [2048,4096]
    mla_attn_mfma<<<dim3(64, 8), 256, 0, stream>>>(q_att_bf, kv_bf, vT_bf, w_uvT, o_v_bf);
    // output = o_v @ o_w     [2048,4096] K=4096, f32 out
    gemm_bf16_128<0><<<dim3(32, 16, 1), 256, 0, stream>>>(
        o_v_bf, w_oT, out, 4096, 4096, 4096, 4096, 4096, 0, 0, 0);
}